// Round 1
// baseline (257.866 us; speedup 1.0000x reference)
//
#include <hip/hip_runtime.h>
#include <stdint.h>

typedef unsigned long long u64;
typedef unsigned int u32;

#define NA 250000
#define NC 80
#define KP 2000
#define MD 300
#define CAP 4096
#define SCORE_TH 0.05f

// ---- ws layout (bytes) ----
// sbits  u32[250000]      @ 0
// amax   u32[250000]      @ 1000000
// state  u32[16]          @ 2000000   [0]=prefix [1]=k [2]=pivot [3]=n_cand [4]=n_keep
// hist   u32[2048]        @ 2000064
// cand   u64[4096]        @ 2008256
// canda  u32[2048]        @ 2041024   (anchor index per sorted candidate)
// cands  u32[2048]        @ 2049216   (score bits per sorted candidate)
// boxes  float4[2048]     @ 2057408
// sup    u64[2000*32]     @ 2090176   (suppression bitmask, j>i only)
// keep   int[2048]        @ 2602176

__global__ void k_init(u32* state, u32* hist) {
    int t = threadIdx.x;
    if (t == 0) {
        for (int i = 0; i < 16; ++i) state[i] = 0;
        state[1] = KP;
    }
    for (int i = t; i < 2048; i += 256) hist[i] = 0;
}

// scores + argmax: 4 lanes per anchor, each reads 20 contiguous floats (5x float4)
__global__ void k_score(const float* __restrict__ cls, u32* __restrict__ sbits,
                        u32* __restrict__ amax) {
    int tid = blockIdx.x * 256 + threadIdx.x;
    int a = tid >> 2;
    int k = tid & 3;
    if (a >= NA) return;
    const float4* cv = (const float4*)cls;
    int base = a * 20 + k * 5;
    float best = -1e30f; int bi = 0;
#pragma unroll
    for (int j = 0; j < 5; ++j) {
        float4 v = cv[base + j];
        int c0 = k * 20 + j * 4;
        if (v.x > best) { best = v.x; bi = c0; }
        if (v.y > best) { best = v.y; bi = c0 + 1; }
        if (v.z > best) { best = v.z; bi = c0 + 2; }
        if (v.w > best) { best = v.w; bi = c0 + 3; }
    }
    // combine 4 lanes; tie -> lower class index (matches jnp.argmax)
#pragma unroll
    for (int m = 1; m <= 2; m <<= 1) {
        float ob = __shfl_xor(best, m);
        int   oi = __shfl_xor(bi, m);
        if (ob > best || (ob == best && oi < bi)) { best = ob; bi = oi; }
    }
    if (k == 0) {
        sbits[a] = (best > SCORE_TH) ? __float_as_uint(best) : 0u;   // invalid -> 0
        amax[a] = (u32)bi;
    }
}

// radix-select histogram pass (p=0: bits>>21 [2048 bins]; p=1: (>>10)&0x7FF; p=2: &0x3FF)
__global__ void k_hist(const u32* __restrict__ sbits, u32* __restrict__ hist,
                       const u32* __restrict__ state, int p) {
    __shared__ u32 lh[2048];
    int t = threadIdx.x;
    for (int i = t; i < 2048; i += 256) lh[i] = 0;
    __syncthreads();
    u32 prefix = state[0];
    int idx = blockIdx.x * 1024 + t;
#pragma unroll
    for (int r = 0; r < 4; ++r) {
        int a = idx + r * 256;
        if (a < NA) {
            u32 b = sbits[a];
            bool ok; u32 d;
            if (p == 0)      { ok = true;                      d = b >> 21; }
            else if (p == 1) { ok = ((b >> 21) == prefix);     d = (b >> 10) & 0x7FFu; }
            else             { ok = ((b >> 10) == prefix);     d = b & 0x3FFu; }
            if (ok) atomicAdd(&lh[d], 1u);
        }
    }
    __syncthreads();
    for (int i = t; i < 2048; i += 256) { u32 h = lh[i]; if (h) atomicAdd(&hist[i], h); }
}

// pick the bin containing rank k (descending), update prefix/k; zero hist for next pass
__global__ void k_pick(u32* state, u32* hist, int p, int nbins) {
    int lane = threadIdx.x;                  // 64 threads
    int per = nbins >> 6;
    int hi = nbins - lane * per;
    int lo = hi - per;
    u32 s = 0;
    for (int b = lo; b < hi; ++b) s += hist[b];
    u32 sc = s;
#pragma unroll
    for (int d = 1; d < 64; d <<= 1) {
        u32 tv = __shfl_up(sc, d);
        if (lane >= d) sc += tv;
    }
    u32 pre = sc - s;
    u32 kk = state[1];
    if (pre < kk && kk <= sc) {              // exactly one lane
        u32 c = pre; int B = lo;
        for (int b = hi - 1; b >= lo; --b) {
            u32 h = hist[b];
            if (c + h >= kk) { B = b; state[1] = kk - c; break; }
            c += h;
        }
        u32 prefix = state[0];
        if (p == 0)      state[0] = (u32)B;
        else if (p == 1) state[0] = (prefix << 11) | (u32)B;
        else             state[2] = (prefix << 10) | (u32)B;   // final pivot
    }
    for (int i = lane; i < 2048; i += 64) hist[i] = 0;
}

__global__ void k_collect(const u32* __restrict__ sbits, u32* state, u64* __restrict__ cand) {
    int a = blockIdx.x * 256 + threadIdx.x;
    if (a >= NA) return;
    u32 b = sbits[a];
    u32 pivot = state[2];
    if (b != 0u && b >= pivot) {
        u32 slot = atomicAdd(&state[3], 1u);
        if (slot < CAP) cand[slot] = ((u64)b << 32) | (u32)(~(u32)a); // (score desc, idx asc)
    }
}

__global__ __launch_bounds__(1024) void k_sort(const u32* __restrict__ state,
                                               const u64* __restrict__ cand,
                                               u32* __restrict__ canda, u32* __restrict__ cands) {
    __shared__ u64 keys[4096];
    int t = threadIdx.x;
    u32 n = state[3]; if (n > CAP) n = CAP;
    for (int i = t; i < 4096; i += 1024) keys[i] = (i < (int)n) ? cand[i] : 0ull;
    __syncthreads();
    for (int size = 2; size <= 4096; size <<= 1) {
        for (int stride = size >> 1; stride > 0; stride >>= 1) {
            for (int v = t; v < 2048; v += 1024) {
                int i = ((v / stride) * (stride << 1)) + (v % stride);
                int j = i + stride;
                u64 A = keys[i], B = keys[j];
                bool descb = ((i & size) == 0);
                bool sw = descb ? (A < B) : (A > B);
                if (sw) { keys[i] = B; keys[j] = A; }
            }
            __syncthreads();
        }
    }
    for (int i = t; i < 2048; i += 1024) {
        u64 kx = keys[i];
        canda[i] = ~((u32)kx);
        cands[i] = (u32)(kx >> 32);
    }
}

__global__ void k_decode(const float* __restrict__ anchors, const float* __restrict__ reg,
                         const u32* __restrict__ canda, float4* __restrict__ boxes) {
    int i = blockIdx.x * 256 + threadIdx.x;
    if (i >= KP) return;
    u32 a = canda[i];
    if (a >= NA) a = 0;                       // degenerate-safety only
    float4 an = ((const float4*)anchors)[a];
    float4 rg = ((const float4*)reg)[a];
    float w = an.z - an.x, h = an.w - an.y;
    float cx = an.x + 0.5f * w, cy = an.y + 0.5f * h;
    float pcx = cx + (rg.x * 0.1f) * w;
    float pcy = cy + (rg.y * 0.1f) * h;
    float pw = expf(rg.z * 0.2f) * w;
    float ph = expf(rg.w * 0.2f) * h;
    float x1 = fmaxf(pcx - 0.5f * pw, 0.0f);
    float y1 = fmaxf(pcy - 0.5f * ph, 0.0f);
    float x2 = fminf(pcx + 0.5f * pw, 512.0f);
    float y2 = fminf(pcy + 0.5f * ph, 512.0f);
    boxes[i] = make_float4(x1, y1, x2, y2);
}

// suppression bitmask: sup[i*32+w] bit jj set iff j=w*64+jj > i and IoU(i,j) > 0.1
__global__ void k_iou(const float4* __restrict__ boxes, u64* __restrict__ sup) {
    int bi = blockIdx.y, bj = blockIdx.x;
    int t = threadIdx.x;
    int i = bi * 64 + t;
    if (bj < bi) { if (i < KP) sup[(size_t)i * 32 + bj] = 0ull; return; }
    __shared__ float4 jb[64];
    int j0 = bj * 64;
    int jn = KP - j0; if (jn > 64) jn = 64;
    jb[t] = (t < jn) ? boxes[j0 + t] : make_float4(0.f, 0.f, 0.f, 0.f);
    __syncthreads();
    if (i >= KP) return;
    float4 bx = boxes[i];
    float ai = (bx.z - bx.x) * (bx.w - bx.y);
    u64 word = 0ull;
    for (int jj = 0; jj < jn; ++jj) {
        int j = j0 + jj;
        if (j <= i) continue;
        float4 b2 = jb[jj];
        float aj = (b2.z - b2.x) * (b2.w - b2.y);
        float xx1 = fmaxf(bx.x, b2.x), yy1 = fmaxf(bx.y, b2.y);
        float xx2 = fminf(bx.z, b2.z), yy2 = fminf(bx.w, b2.w);
        float iw = xx2 - xx1; if (iw < 0.f) iw = 0.f;
        float ih = yy2 - yy1; if (ih < 0.f) ih = 0.f;
        float inter = iw * ih;
        float iou = inter / (ai + aj - inter + 1e-9f);
        if (iou > 0.1f) word |= (1ull << jj);
    }
    sup[(size_t)i * 32 + bj] = word;
}

// serial greedy NMS, single wave; per-chunk removed word recomputed from kept rows
__global__ void k_scan(const u64* __restrict__ sup, const u32* __restrict__ cands,
                       int* __restrict__ keep_g, u32* state) {
    __shared__ int klist[2048];
    int lane = threadIdx.x;      // 64 threads
    int kc = 0;
    for (int c = 0; c < 32; ++c) {
        __syncthreads();
        int base = c * 64;
        int nb = KP - base; if (nb > 64) nb = 64;
        int ir = base + lane;
        u64 myw = 0ull;
        bool v = false;
        if (lane < nb) {
            myw = sup[(size_t)ir * 32 + c];     // critical word (within-chunk suppression)
            v = (__uint_as_float(cands[ir]) > SCORE_TH);
        }
        u64 vm = __ballot(v);
        // OR of word c over all kept rows so far (batched, latency paid once per chunk)
        u64 acc = 0ull;
        for (int p0 = 0; p0 < kc; p0 += 64) {
            int pi = p0 + lane;
            if (pi < kc) acc |= sup[(size_t)klist[pi] * 32 + c];
        }
#pragma unroll
        for (int m = 32; m >= 1; m >>= 1) acc |= __shfl_xor(acc, m);
        u64 cur = acc;
        for (int b = 0; b < nb; ++b) {
            if (!((cur >> b) & 1ull) && ((vm >> b) & 1ull)) {
                if (lane == 0) klist[kc] = base + b;
                kc++;
                cur |= __shfl(myw, b);          // row (base+b)'s word c, j>i bits only
            }
        }
    }
    __syncthreads();
    for (int p = lane; p < kc; p += 64) keep_g[p] = klist[p];
    if (lane == 0) state[4] = (u32)kc;
}

__global__ void k_out(const int* __restrict__ keep_g, const u32* __restrict__ state,
                      const u32* __restrict__ cands, const u32* __restrict__ canda,
                      const u32* __restrict__ amax, const float4* __restrict__ boxes,
                      float* __restrict__ out) {
    int s = blockIdx.x * 256 + threadIdx.x;
    if (s >= MD) return;
    int nk = (int)state[4];
    if (s < nk) {
        int ci = keep_g[s];
        u32 a = canda[ci];
        u32 aa = (a >= NA) ? 0u : a;
        float4 bx = boxes[ci];
        out[s] = __uint_as_float(cands[ci]);
        out[MD + s] = (float)amax[aa];
        out[2 * MD + s * 4 + 0] = bx.x;
        out[2 * MD + s * 4 + 1] = bx.y;
        out[2 * MD + s * 4 + 2] = bx.z;
        out[2 * MD + s * 4 + 3] = bx.w;
        out[6 * MD + s] = (float)a;
        out[7 * MD + s] = 1.0f;
    } else {
        out[s] = 0.f;
        out[MD + s] = 0.f;
        out[2 * MD + s * 4 + 0] = 0.f;
        out[2 * MD + s * 4 + 1] = 0.f;
        out[2 * MD + s * 4 + 2] = 0.f;
        out[2 * MD + s * 4 + 3] = 0.f;
        out[6 * MD + s] = -1.0f;
        out[7 * MD + s] = 0.f;
    }
}

extern "C" void kernel_launch(void* const* d_in, const int* in_sizes, int n_in,
                              void* d_out, int out_size, void* d_ws, size_t ws_size,
                              hipStream_t stream) {
    const float* anchors = (const float*)d_in[1];
    const float* reg     = (const float*)d_in[2];
    const float* cls     = (const float*)d_in[3];
    float* out = (float*)d_out;
    char* ws = (char*)d_ws;

    u32* sbits  = (u32*)(ws + 0);
    u32* amax   = (u32*)(ws + 1000000);
    u32* state  = (u32*)(ws + 2000000);
    u32* hist   = (u32*)(ws + 2000064);
    u64* cand   = (u64*)(ws + 2008256);
    u32* canda  = (u32*)(ws + 2041024);
    u32* cands  = (u32*)(ws + 2049216);
    float4* boxes = (float4*)(ws + 2057408);
    u64* sup    = (u64*)(ws + 2090176);
    int* keep_g = (int*)(ws + 2602176);

    hipLaunchKernelGGL(k_init, dim3(1), dim3(256), 0, stream, state, hist);
    hipLaunchKernelGGL(k_score, dim3((NA * 4 + 255) / 256), dim3(256), 0, stream,
                       cls, sbits, amax);
    for (int p = 0; p < 3; ++p) {
        hipLaunchKernelGGL(k_hist, dim3((NA + 1023) / 1024), dim3(256), 0, stream,
                           sbits, hist, state, p);
        hipLaunchKernelGGL(k_pick, dim3(1), dim3(64), 0, stream,
                           state, hist, p, (p == 2) ? 1024 : 2048);
    }
    hipLaunchKernelGGL(k_collect, dim3((NA + 255) / 256), dim3(256), 0, stream,
                       sbits, state, cand);
    hipLaunchKernelGGL(k_sort, dim3(1), dim3(1024), 0, stream, state, cand, canda, cands);
    hipLaunchKernelGGL(k_decode, dim3((KP + 255) / 256), dim3(256), 0, stream,
                       anchors, reg, canda, boxes);
    hipLaunchKernelGGL(k_iou, dim3(32, 32), dim3(64), 0, stream, boxes, sup);
    hipLaunchKernelGGL(k_scan, dim3(1), dim3(64), 0, stream, sup, cands, keep_g, state);
    hipLaunchKernelGGL(k_out, dim3((MD + 255) / 256), dim3(256), 0, stream,
                       keep_g, state, cands, canda, amax, boxes, out);
}

// Round 2
// 193.647 us; speedup vs baseline: 1.3316x; 1.3316x over previous
//
#include <hip/hip_runtime.h>
#include <stdint.h>

typedef unsigned long long u64;
typedef unsigned int u32;

#define NA 250000
#define NC 80
#define KP 2000
#define MD 300
#define CAP 4096
#define SCORE_TH 0.05f

// ---- ws layout (bytes) ----
// sbits  u32[250000]      @ 0
// amax   u32[250000]      @ 1000000
// state  u32[16]          @ 2000000   [0]=prefix [1]=k [2]=pivot [3]=n_cand [4]=n_keep
// hist   u32[2048]        @ 2000064
// cand   u64[4096]        @ 2008256
// canda  u32[2048]        @ 2041024   (anchor index per sorted candidate)
// cands  u32[2048]        @ 2049216   (score bits per sorted candidate)
// boxes  float4[2048]     @ 2057408
// sup    u64[2000*32]     @ 2090176   (suppression bitmask, j>i only)
// keep   int[2048]        @ 2602176

__global__ void k_init(u32* state, u32* hist) {
    int t = threadIdx.x;
    if (t == 0) {
        for (int i = 0; i < 16; ++i) state[i] = 0;
        state[1] = KP;
    }
    for (int i = t; i < 2048; i += 256) hist[i] = 0;
}

// scores + argmax: 4 lanes per anchor, each reads 20 contiguous floats (5x float4)
__global__ void k_score(const float* __restrict__ cls, u32* __restrict__ sbits,
                        u32* __restrict__ amax) {
    int tid = blockIdx.x * 256 + threadIdx.x;
    int a = tid >> 2;
    int k = tid & 3;
    if (a >= NA) return;
    const float4* cv = (const float4*)cls;
    int base = a * 20 + k * 5;
    float best = -1e30f; int bi = 0;
#pragma unroll
    for (int j = 0; j < 5; ++j) {
        float4 v = cv[base + j];
        int c0 = k * 20 + j * 4;
        if (v.x > best) { best = v.x; bi = c0; }
        if (v.y > best) { best = v.y; bi = c0 + 1; }
        if (v.z > best) { best = v.z; bi = c0 + 2; }
        if (v.w > best) { best = v.w; bi = c0 + 3; }
    }
    // combine 4 lanes; tie -> lower class index (matches jnp.argmax)
#pragma unroll
    for (int m = 1; m <= 2; m <<= 1) {
        float ob = __shfl_xor(best, m);
        int   oi = __shfl_xor(bi, m);
        if (ob > best || (ob == best && oi < bi)) { best = ob; bi = oi; }
    }
    if (k == 0) {
        sbits[a] = (best > SCORE_TH) ? __float_as_uint(best) : 0u;   // invalid -> 0
        amax[a] = (u32)bi;
    }
}

// radix-select histogram pass (p=0: bits>>21 [2048 bins]; p=1: (>>10)&0x7FF; p=2: &0x3FF)
__global__ void k_hist(const u32* __restrict__ sbits, u32* __restrict__ hist,
                       const u32* __restrict__ state, int p) {
    __shared__ u32 lh[2048];
    int t = threadIdx.x;
    for (int i = t; i < 2048; i += 256) lh[i] = 0;
    __syncthreads();
    u32 prefix = state[0];
    int idx = blockIdx.x * 1024 + t;
#pragma unroll
    for (int r = 0; r < 4; ++r) {
        int a = idx + r * 256;
        if (a < NA) {
            u32 b = sbits[a];
            bool ok; u32 d;
            if (p == 0)      { ok = true;                      d = b >> 21; }
            else if (p == 1) { ok = ((b >> 21) == prefix);     d = (b >> 10) & 0x7FFu; }
            else             { ok = ((b >> 10) == prefix);     d = b & 0x3FFu; }
            if (ok) atomicAdd(&lh[d], 1u);
        }
    }
    __syncthreads();
    for (int i = t; i < 2048; i += 256) { u32 h = lh[i]; if (h) atomicAdd(&hist[i], h); }
}

// pick the bin containing rank k (descending), update prefix/k; zero hist for next pass
__global__ void k_pick(u32* state, u32* hist, int p, int nbins) {
    int lane = threadIdx.x;                  // 64 threads
    int per = nbins >> 6;
    int hi = nbins - lane * per;
    int lo = hi - per;
    u32 s = 0;
    for (int b = lo; b < hi; ++b) s += hist[b];
    u32 sc = s;
#pragma unroll
    for (int d = 1; d < 64; d <<= 1) {
        u32 tv = __shfl_up(sc, d);
        if (lane >= d) sc += tv;
    }
    u32 pre = sc - s;
    u32 kk = state[1];
    if (pre < kk && kk <= sc) {              // exactly one lane
        u32 c = pre; int B = lo;
        for (int b = hi - 1; b >= lo; --b) {
            u32 h = hist[b];
            if (c + h >= kk) { B = b; state[1] = kk - c; break; }
            c += h;
        }
        u32 prefix = state[0];
        if (p == 0)      state[0] = (u32)B;
        else if (p == 1) state[0] = (prefix << 11) | (u32)B;
        else             state[2] = (prefix << 10) | (u32)B;   // final pivot
    }
    for (int i = lane; i < 2048; i += 64) hist[i] = 0;
}

__global__ void k_collect(const u32* __restrict__ sbits, u32* state, u64* __restrict__ cand) {
    int a = blockIdx.x * 256 + threadIdx.x;
    if (a >= NA) return;
    u32 b = sbits[a];
    u32 pivot = state[2];
    if (b != 0u && b >= pivot) {
        u32 slot = atomicAdd(&state[3], 1u);
        if (slot < CAP) cand[slot] = ((u64)b << 32) | (u32)(~(u32)a); // (score desc, idx asc)
    }
}

__global__ __launch_bounds__(1024) void k_sort(const u32* __restrict__ state,
                                               const u64* __restrict__ cand,
                                               u32* __restrict__ canda, u32* __restrict__ cands) {
    __shared__ u64 keys[4096];
    int t = threadIdx.x;
    u32 n = state[3]; if (n > CAP) n = CAP;
    for (int i = t; i < 4096; i += 1024) keys[i] = (i < (int)n) ? cand[i] : 0ull;
    __syncthreads();
    for (int size = 2; size <= 4096; size <<= 1) {
        for (int stride = size >> 1; stride > 0; stride >>= 1) {
            for (int v = t; v < 2048; v += 1024) {
                int i = ((v / stride) * (stride << 1)) + (v % stride);
                int j = i + stride;
                u64 A = keys[i], B = keys[j];
                bool descb = ((i & size) == 0);
                bool sw = descb ? (A < B) : (A > B);
                if (sw) { keys[i] = B; keys[j] = A; }
            }
            __syncthreads();
        }
    }
    for (int i = t; i < 2048; i += 1024) {
        u64 kx = keys[i];
        canda[i] = ~((u32)kx);
        cands[i] = (u32)(kx >> 32);
    }
}

__global__ void k_decode(const float* __restrict__ anchors, const float* __restrict__ reg,
                         const u32* __restrict__ canda, float4* __restrict__ boxes) {
    int i = blockIdx.x * 256 + threadIdx.x;
    if (i >= KP) return;
    u32 a = canda[i];
    if (a >= NA) a = 0;                       // degenerate-safety only
    float4 an = ((const float4*)anchors)[a];
    float4 rg = ((const float4*)reg)[a];
    float w = an.z - an.x, h = an.w - an.y;
    float cx = an.x + 0.5f * w, cy = an.y + 0.5f * h;
    float pcx = cx + (rg.x * 0.1f) * w;
    float pcy = cy + (rg.y * 0.1f) * h;
    float pw = expf(rg.z * 0.2f) * w;
    float ph = expf(rg.w * 0.2f) * h;
    float x1 = fmaxf(pcx - 0.5f * pw, 0.0f);
    float y1 = fmaxf(pcy - 0.5f * ph, 0.0f);
    float x2 = fminf(pcx + 0.5f * pw, 512.0f);
    float y2 = fminf(pcy + 0.5f * ph, 512.0f);
    boxes[i] = make_float4(x1, y1, x2, y2);
}

// suppression bitmask: sup[i*32+w] bit jj set iff j=w*64+jj > i and IoU(i,j) > 0.1
__global__ void k_iou(const float4* __restrict__ boxes, u64* __restrict__ sup) {
    int bi = blockIdx.y, bj = blockIdx.x;
    int t = threadIdx.x;
    int i = bi * 64 + t;
    if (bj < bi) { if (i < KP) sup[(size_t)i * 32 + bj] = 0ull; return; }
    __shared__ float4 jb[64];
    int j0 = bj * 64;
    int jn = KP - j0; if (jn > 64) jn = 64;
    jb[t] = (t < jn) ? boxes[j0 + t] : make_float4(0.f, 0.f, 0.f, 0.f);
    __syncthreads();
    if (i >= KP) return;
    float4 bx = boxes[i];
    float ai = (bx.z - bx.x) * (bx.w - bx.y);
    u64 word = 0ull;
    for (int jj = 0; jj < jn; ++jj) {
        int j = j0 + jj;
        if (j <= i) continue;
        float4 b2 = jb[jj];
        float aj = (b2.z - b2.x) * (b2.w - b2.y);
        float xx1 = fmaxf(bx.x, b2.x), yy1 = fmaxf(bx.y, b2.y);
        float xx2 = fminf(bx.z, b2.z), yy2 = fminf(bx.w, b2.w);
        float iw = xx2 - xx1; if (iw < 0.f) iw = 0.f;
        float ih = yy2 - yy1; if (ih < 0.f) ih = 0.f;
        float inter = iw * ih;
        float iou = inter / (ai + aj - inter + 1e-9f);
        if (iou > 0.1f) word |= (1ull << jj);
    }
    sup[(size_t)i * 32 + bj] = word;
}

// serial greedy NMS, single wave.
// removed bitmap: lane w (w<32) holds removed word w (candidates 64w..64w+63) in a register.
// Per 64-candidate chunk: rows staged in LDS (double-buffered, loads issued before the
// serial phase = T14 async split); serial phase is pure shfl/VALU; then each lane ORs its
// column of the kept rows from LDS. LDS layout [w][65] padded -> <=2-way bank aliasing.
__global__ __launch_bounds__(64) void k_scan(const u64* __restrict__ sup,
                                             const u32* __restrict__ cands,
                                             int* __restrict__ keep_g, u32* state) {
    __shared__ u64 rows[2][32 * 65];   // [buf][w*65 + b], 33.3 KB
    __shared__ int klist[2048];
    int lane = threadIdx.x;

    // stage chunk 0: lane owns row b=lane, 32 words, contiguous 256B
    {
        const ulonglong2* src = (const ulonglong2*)(sup + (size_t)lane * 32);
#pragma unroll
        for (int q = 0; q < 16; ++q) {
            ulonglong2 v = src[q];
            rows[0][(2 * q) * 65 + lane] = v.x;
            rows[0][(2 * q + 1) * 65 + lane] = v.y;
        }
    }
    __syncthreads();

    u64 removed = 0ull;   // lane w<32: word w of global removed bitmap
    int kc = 0;
    int cur = 0;

    for (int c = 0; c < 32; ++c) {
        int base = c * 64;
        int nb = KP - base; if (nb > 64) nb = 64;

        // issue prefetch of next chunk into registers (loads start now, used after serial)
        ulonglong2 pre[16];
        bool have_next = (c + 1 < 32);
        if (have_next) {
            int r = base + 64 + lane;
            if (r >= KP) r = 0;                       // clamp (rows >= KP never used)
            const ulonglong2* src = (const ulonglong2*)(sup + (size_t)r * 32);
#pragma unroll
            for (int q = 0; q < 16; ++q) pre[q] = src[q];
        }

        u64 curw = __shfl(removed, c);                 // removed word for this chunk
        u64 myw = (lane < nb) ? rows[cur][c * 65 + lane] : 0ull;  // own row, word c
        bool v = (lane < nb) && (__uint_as_float(cands[base + lane]) > SCORE_TH);
        u64 vm = __ballot(v);

        // serial greedy within chunk: iterate surviving set bits only
        u64 rem = vm & ~curw;
        u64 kmask = 0ull;
        while (rem) {
            int b = __ffsll((long long)rem) - 1;
            kmask |= (1ull << b);
            curw |= __shfl(myw, b);                    // row b's word c (bits > b only)
            rem &= ~curw;
            rem &= ~(1ull << b);
        }

        // record kept (parallel rank via popcount)
        if ((kmask >> lane) & 1ull) {
            int pos = kc + (int)__popcll(kmask & ((1ull << lane) - 1ull));
            klist[pos] = base + lane;
        }
        kc += (int)__popcll(kmask);

        // fold kept rows into removed: lane w reads column w of kept rows (LDS, pipelined)
        if (lane < 32) {
            u64 t = kmask;
            while (t) {
                int b = __ffsll((long long)t) - 1;
                removed |= rows[cur][lane * 65 + b];
                t &= t - 1;
            }
        }

        // write prefetched rows into the other buffer
        if (have_next) {
#pragma unroll
            for (int q = 0; q < 16; ++q) {
                rows[cur ^ 1][(2 * q) * 65 + lane] = pre[q].x;
                rows[cur ^ 1][(2 * q + 1) * 65 + lane] = pre[q].y;
            }
            cur ^= 1;
            __syncthreads();
        }
    }

    __syncthreads();
    for (int p = lane; p < kc; p += 64) keep_g[p] = klist[p];
    if (lane == 0) state[4] = (u32)kc;
}

__global__ void k_out(const int* __restrict__ keep_g, const u32* __restrict__ state,
                      const u32* __restrict__ cands, const u32* __restrict__ canda,
                      const u32* __restrict__ amax, const float4* __restrict__ boxes,
                      float* __restrict__ out) {
    int s = blockIdx.x * 256 + threadIdx.x;
    if (s >= MD) return;
    int nk = (int)state[4];
    if (s < nk) {
        int ci = keep_g[s];
        u32 a = canda[ci];
        u32 aa = (a >= NA) ? 0u : a;
        float4 bx = boxes[ci];
        out[s] = __uint_as_float(cands[ci]);
        out[MD + s] = (float)amax[aa];
        out[2 * MD + s * 4 + 0] = bx.x;
        out[2 * MD + s * 4 + 1] = bx.y;
        out[2 * MD + s * 4 + 2] = bx.z;
        out[2 * MD + s * 4 + 3] = bx.w;
        out[6 * MD + s] = (float)a;
        out[7 * MD + s] = 1.0f;
    } else {
        out[s] = 0.f;
        out[MD + s] = 0.f;
        out[2 * MD + s * 4 + 0] = 0.f;
        out[2 * MD + s * 4 + 1] = 0.f;
        out[2 * MD + s * 4 + 2] = 0.f;
        out[2 * MD + s * 4 + 3] = 0.f;
        out[6 * MD + s] = -1.0f;
        out[7 * MD + s] = 0.f;
    }
}

extern "C" void kernel_launch(void* const* d_in, const int* in_sizes, int n_in,
                              void* d_out, int out_size, void* d_ws, size_t ws_size,
                              hipStream_t stream) {
    const float* anchors = (const float*)d_in[1];
    const float* reg     = (const float*)d_in[2];
    const float* cls     = (const float*)d_in[3];
    float* out = (float*)d_out;
    char* ws = (char*)d_ws;

    u32* sbits  = (u32*)(ws + 0);
    u32* amax   = (u32*)(ws + 1000000);
    u32* state  = (u32*)(ws + 2000000);
    u32* hist   = (u32*)(ws + 2000064);
    u64* cand   = (u64*)(ws + 2008256);
    u32* canda  = (u32*)(ws + 2041024);
    u32* cands  = (u32*)(ws + 2049216);
    float4* boxes = (float4*)(ws + 2057408);
    u64* sup    = (u64*)(ws + 2090176);
    int* keep_g = (int*)(ws + 2602176);

    hipLaunchKernelGGL(k_init, dim3(1), dim3(256), 0, stream, state, hist);
    hipLaunchKernelGGL(k_score, dim3((NA * 4 + 255) / 256), dim3(256), 0, stream,
                       cls, sbits, amax);
    for (int p = 0; p < 3; ++p) {
        hipLaunchKernelGGL(k_hist, dim3((NA + 1023) / 1024), dim3(256), 0, stream,
                           sbits, hist, state, p);
        hipLaunchKernelGGL(k_pick, dim3(1), dim3(64), 0, stream,
                           state, hist, p, (p == 2) ? 1024 : 2048);
    }
    hipLaunchKernelGGL(k_collect, dim3((NA + 255) / 256), dim3(256), 0, stream,
                       sbits, state, cand);
    hipLaunchKernelGGL(k_sort, dim3(1), dim3(1024), 0, stream, state, cand, canda, cands);
    hipLaunchKernelGGL(k_decode, dim3((KP + 255) / 256), dim3(256), 0, stream,
                       anchors, reg, canda, boxes);
    hipLaunchKernelGGL(k_iou, dim3(32, 32), dim3(64), 0, stream, boxes, sup);
    hipLaunchKernelGGL(k_scan, dim3(1), dim3(64), 0, stream, sup, cands, keep_g, state);
    hipLaunchKernelGGL(k_out, dim3((MD + 255) / 256), dim3(256), 0, stream,
                       keep_g, state, cands, canda, amax, boxes, out);
}

// Round 3
// 185.562 us; speedup vs baseline: 1.3897x; 1.0436x over previous
//
#include <hip/hip_runtime.h>
#include <stdint.h>

typedef unsigned long long u64;
typedef unsigned int u32;

#define NA 250000
#define NC 80
#define KP 2000
#define MD 300
#define CAP 4096
#define SCORE_TH 0.05f

// ---- ws layout (bytes) ----
// sbits  u32[250000]      @ 0
// amax   u32[250000]      @ 1000000
// state  u32[16]          @ 2000000   [0]=prefix [1]=k [2]=pivot [3]=n_cand [4]=n_keep
// hist   u32[2048]        @ 2000064
// cand   u64[4096]        @ 2008256
// canda  u32[2048]        @ 2041024   (anchor index per sorted candidate)
// cands  u32[2048]        @ 2049216   (score bits per sorted candidate)
// sup    u64[2000*32]     @ 2090176   (suppression bitmask, j>i only)

__device__ __forceinline__ u64 readlane_u64(u64 v, int b) {
    u32 lo = (u32)__builtin_amdgcn_readlane((int)(u32)v, b);
    u32 hi = (u32)__builtin_amdgcn_readlane((int)(u32)(v >> 32), b);
    return ((u64)hi << 32) | lo;
}

__device__ __forceinline__ float4 decode_box(const float* __restrict__ anchors,
                                             const float* __restrict__ reg, u32 a) {
    float4 an = ((const float4*)anchors)[a];
    float4 rg = ((const float4*)reg)[a];
    float w = an.z - an.x, h = an.w - an.y;
    float cx = an.x + 0.5f * w, cy = an.y + 0.5f * h;
    float pcx = cx + (rg.x * 0.1f) * w;
    float pcy = cy + (rg.y * 0.1f) * h;
    float pw = expf(rg.z * 0.2f) * w;
    float ph = expf(rg.w * 0.2f) * h;
    float x1 = fmaxf(pcx - 0.5f * pw, 0.0f);
    float y1 = fmaxf(pcy - 0.5f * ph, 0.0f);
    float x2 = fminf(pcx + 0.5f * pw, 512.0f);
    float y2 = fminf(pcy + 0.5f * ph, 512.0f);
    return make_float4(x1, y1, x2, y2);
}

// scores + argmax (k_init fused into block 0): 4 lanes per anchor, 5x float4 each
__global__ void k_score(const float* __restrict__ cls, u32* __restrict__ sbits,
                        u32* __restrict__ amax, u32* __restrict__ state,
                        u32* __restrict__ hist) {
    int t = threadIdx.x;
    if (blockIdx.x == 0) {                       // fused init (no later-kernel hazard)
        if (t < 16) state[t] = (t == 1) ? (u32)KP : 0u;
        for (int i = t; i < 2048; i += 256) hist[i] = 0;
    }
    int tid = blockIdx.x * 256 + t;
    int a = tid >> 2;
    int k = tid & 3;
    if (a >= NA) return;
    const float4* cv = (const float4*)cls;
    int base = a * 20 + k * 5;
    float best = -1e30f; int bi = 0;
#pragma unroll
    for (int j = 0; j < 5; ++j) {
        float4 v = cv[base + j];
        int c0 = k * 20 + j * 4;
        if (v.x > best) { best = v.x; bi = c0; }
        if (v.y > best) { best = v.y; bi = c0 + 1; }
        if (v.z > best) { best = v.z; bi = c0 + 2; }
        if (v.w > best) { best = v.w; bi = c0 + 3; }
    }
#pragma unroll
    for (int m = 1; m <= 2; m <<= 1) {
        float ob = __shfl_xor(best, m);
        int   oi = __shfl_xor(bi, m);
        if (ob > best || (ob == best && oi < bi)) { best = ob; bi = oi; }
    }
    if (k == 0) {
        sbits[a] = (best > SCORE_TH) ? __float_as_uint(best) : 0u;
        amax[a] = (u32)bi;
    }
}

// radix-select histogram pass (p=0: bits>>21 [2048 bins]; p=1: (>>10)&0x7FF; p=2: &0x3FF)
__global__ void k_hist(const u32* __restrict__ sbits, u32* __restrict__ hist,
                       const u32* __restrict__ state, int p) {
    __shared__ u32 lh[2048];
    int t = threadIdx.x;
    for (int i = t; i < 2048; i += 256) lh[i] = 0;
    __syncthreads();
    u32 prefix = state[0];
    int idx = blockIdx.x * 1024 + t;
#pragma unroll
    for (int r = 0; r < 4; ++r) {
        int a = idx + r * 256;
        if (a < NA) {
            u32 b = sbits[a];
            bool ok; u32 d;
            if (p == 0)      { ok = true;                      d = b >> 21; }
            else if (p == 1) { ok = ((b >> 21) == prefix);     d = (b >> 10) & 0x7FFu; }
            else             { ok = ((b >> 10) == prefix);     d = b & 0x3FFu; }
            if (ok) atomicAdd(&lh[d], 1u);
        }
    }
    __syncthreads();
    for (int i = t; i < 2048; i += 256) { u32 h = lh[i]; if (h) atomicAdd(&hist[i], h); }
}

__global__ void k_pick(u32* state, u32* hist, int p, int nbins) {
    int lane = threadIdx.x;                  // 64 threads
    int per = nbins >> 6;
    int hi = nbins - lane * per;
    int lo = hi - per;
    u32 s = 0;
    for (int b = lo; b < hi; ++b) s += hist[b];
    u32 sc = s;
#pragma unroll
    for (int d = 1; d < 64; d <<= 1) {
        u32 tv = __shfl_up(sc, d);
        if (lane >= d) sc += tv;
    }
    u32 pre = sc - s;
    u32 kk = state[1];
    if (pre < kk && kk <= sc) {              // exactly one lane
        u32 c = pre; int B = lo;
        for (int b = hi - 1; b >= lo; --b) {
            u32 h = hist[b];
            if (c + h >= kk) { B = b; state[1] = kk - c; break; }
            c += h;
        }
        u32 prefix = state[0];
        if (p == 0)      state[0] = (u32)B;
        else if (p == 1) state[0] = (prefix << 11) | (u32)B;
        else             state[2] = (prefix << 10) | (u32)B;   // final pivot
    }
    for (int i = lane; i < 2048; i += 64) hist[i] = 0;
}

__global__ void k_collect(const u32* __restrict__ sbits, u32* state, u64* __restrict__ cand) {
    int a = blockIdx.x * 256 + threadIdx.x;
    if (a >= NA) return;
    u32 b = sbits[a];
    u32 pivot = state[2];
    if (b != 0u && b >= pivot) {
        u32 slot = atomicAdd(&state[3], 1u);
        if (slot < CAP) cand[slot] = ((u64)b << 32) | (u32)(~(u32)a); // (score desc, idx asc)
    }
}

__global__ __launch_bounds__(1024) void k_sort(const u32* __restrict__ state,
                                               const u64* __restrict__ cand,
                                               u32* __restrict__ canda, u32* __restrict__ cands) {
    __shared__ u64 keys[4096];
    int t = threadIdx.x;
    u32 n = state[3]; if (n > CAP) n = CAP;
    for (int i = t; i < 4096; i += 1024) keys[i] = (i < (int)n) ? cand[i] : 0ull;
    __syncthreads();
    for (int size = 2; size <= 4096; size <<= 1) {
        for (int stride = size >> 1; stride > 0; stride >>= 1) {
            for (int v = t; v < 2048; v += 1024) {
                int i = ((v / stride) * (stride << 1)) + (v % stride);
                int j = i + stride;
                u64 A = keys[i], B = keys[j];
                bool descb = ((i & size) == 0);
                bool sw = descb ? (A < B) : (A > B);
                if (sw) { keys[i] = B; keys[j] = A; }
            }
            __syncthreads();
        }
    }
    for (int i = t; i < 2048; i += 1024) {
        u64 kx = keys[i];
        canda[i] = ~((u32)kx);
        cands[i] = (u32)(kx >> 32);
    }
}

// IoU suppression bitmask with inline box decode (k_decode fused away).
__global__ void k_iou(const float* __restrict__ anchors, const float* __restrict__ reg,
                      const u32* __restrict__ canda, u64* __restrict__ sup) {
    int bi = blockIdx.y, bj = blockIdx.x;
    int t = threadIdx.x;
    int i = bi * 64 + t;
    if (bj < bi) { if (i < KP) sup[(size_t)i * 32 + bj] = 0ull; return; }
    __shared__ float4 jb[64];
    int j0 = bj * 64;
    int j = j0 + t;                               // j <= 2047, canda has 2048
    int jn = KP - j0; if (jn > 64) jn = 64;
    u32 ja = canda[j]; if (ja >= NA) ja = 0;
    float4 jbox = decode_box(anchors, reg, ja);
    jb[t] = jbox;
    __syncthreads();
    if (i >= KP) return;
    float4 bx;
    if (bi == bj) bx = jbox;
    else { u32 ia = canda[i]; if (ia >= NA) ia = 0; bx = decode_box(anchors, reg, ia); }
    float ai = (bx.z - bx.x) * (bx.w - bx.y);
    u64 word = 0ull;
    for (int jj = 0; jj < jn; ++jj) {
        if (j0 + jj <= i) continue;
        float4 b2 = jb[jj];
        float aj = (b2.z - b2.x) * (b2.w - b2.y);
        float xx1 = fmaxf(bx.x, b2.x), yy1 = fmaxf(bx.y, b2.y);
        float xx2 = fminf(bx.z, b2.z), yy2 = fminf(bx.w, b2.w);
        float iw = xx2 - xx1; if (iw < 0.f) iw = 0.f;
        float ih = yy2 - yy1; if (ih < 0.f) ih = 0.f;
        float inter = iw * ih;
        float iou = inter / (ai + aj - inter + 1e-9f);
        if (iou > 0.1f) word |= (1ull << jj);
    }
    sup[(size_t)i * 32 + bj] = word;
}

// serial greedy NMS + fused output, single wave.
// Serial within-chunk chain uses v_readlane (b is wave-uniform) instead of ds_bpermute;
// fold batches 8 independent LDS reads per waitcnt.
__global__ __launch_bounds__(64) void k_scan(const u64* __restrict__ sup,
                                             const u32* __restrict__ cands,
                                             const u32* __restrict__ canda,
                                             const u32* __restrict__ amax,
                                             const float* __restrict__ anchors,
                                             const float* __restrict__ reg,
                                             float* __restrict__ out) {
    __shared__ u64 rows[2][32 * 65];   // [buf][w*65 + b]
    __shared__ int klist[2048];
    int lane = threadIdx.x;

    // stage chunk 0: lane owns row b=lane, 32 words contiguous
    {
        const ulonglong2* src = (const ulonglong2*)(sup + (size_t)lane * 32);
#pragma unroll
        for (int q = 0; q < 16; ++q) {
            ulonglong2 v = src[q];
            rows[0][(2 * q) * 65 + lane] = v.x;
            rows[0][(2 * q + 1) * 65 + lane] = v.y;
        }
    }
    float cval = __uint_as_float(cands[lane]);
    __syncthreads();

    u64 removed = 0ull;   // lane w<32: word w of global removed bitmap
    int kc = 0;
    int cur = 0;

    for (int c = 0; c < 32; ++c) {
        int base = c * 64;
        int nb = KP - base; if (nb > 64) nb = 64;

        // prefetch next chunk (rows + validity) into registers
        ulonglong2 pre[16];
        float cval_next = 0.f;
        bool have_next = (c + 1 < 32);
        if (have_next) {
            int r = base + 64 + lane;
            int rr = (r >= KP) ? 0 : r;
            const ulonglong2* src = (const ulonglong2*)(sup + (size_t)rr * 32);
#pragma unroll
            for (int q = 0; q < 16; ++q) pre[q] = src[q];
            cval_next = __uint_as_float(cands[r]);        // r <= 2047
        }

        u64 curw = __shfl(removed, c);
        u64 myw = (lane < nb) ? rows[cur][c * 65 + lane] : 0ull;
        bool v = (lane < nb) && (cval > SCORE_TH);
        u64 vm = __ballot(v);

        // serial greedy within chunk: b is uniform -> readlane, ~cheap chain
        u64 rem = vm & ~curw;
        u64 kmask = 0ull;
        while (rem) {
            int b = __ffsll((long long)rem) - 1;
            kmask |= (1ull << b);
            curw |= readlane_u64(myw, b);
            rem &= ~curw;
            rem &= ~(1ull << b);
        }

        if ((kmask >> lane) & 1ull) {
            int pos = kc + (int)__popcll(kmask & ((1ull << lane) - 1ull));
            klist[pos] = base + lane;
        }
        kc += (int)__popcll(kmask);

        // fold kept rows into removed: 8 independent LDS reads per waitcnt
        if (lane < 32) {
            const u64* rb = &rows[cur][lane * 65];
            u64 t = kmask;
            while (t) {
                int b0 = __ffsll((long long)t) - 1; t &= t - 1;
                int b1 = b0, b2 = b0, b3 = b0, b4 = b0, b5 = b0, b6 = b0, b7 = b0;
                if (t) { b1 = __ffsll((long long)t) - 1; t &= t - 1; }
                if (t) { b2 = __ffsll((long long)t) - 1; t &= t - 1; }
                if (t) { b3 = __ffsll((long long)t) - 1; t &= t - 1; }
                if (t) { b4 = __ffsll((long long)t) - 1; t &= t - 1; }
                if (t) { b5 = __ffsll((long long)t) - 1; t &= t - 1; }
                if (t) { b6 = __ffsll((long long)t) - 1; t &= t - 1; }
                if (t) { b7 = __ffsll((long long)t) - 1; t &= t - 1; }
                removed |= rb[b0] | rb[b1] | rb[b2] | rb[b3] | rb[b4] | rb[b5] | rb[b6] | rb[b7];
            }
        }

        if (have_next) {
#pragma unroll
            for (int q = 0; q < 16; ++q) {
                rows[cur ^ 1][(2 * q) * 65 + lane] = pre[q].x;
                rows[cur ^ 1][(2 * q + 1) * 65 + lane] = pre[q].y;
            }
            cur ^= 1;
            cval = cval_next;
            __syncthreads();
        }
    }
    __syncthreads();

    // fused output: 300 slots
    for (int s = lane; s < MD; s += 64) {
        if (s < kc) {
            int ci = klist[s];
            u32 a = canda[ci];
            u32 aa = (a >= NA) ? 0u : a;
            float4 bx = decode_box(anchors, reg, aa);
            out[s] = __uint_as_float(cands[ci]);
            out[MD + s] = (float)amax[aa];
            out[2 * MD + 4 * s + 0] = bx.x;
            out[2 * MD + 4 * s + 1] = bx.y;
            out[2 * MD + 4 * s + 2] = bx.z;
            out[2 * MD + 4 * s + 3] = bx.w;
            out[6 * MD + s] = (float)a;
            out[7 * MD + s] = 1.0f;
        } else {
            out[s] = 0.f;
            out[MD + s] = 0.f;
            out[2 * MD + 4 * s + 0] = 0.f;
            out[2 * MD + 4 * s + 1] = 0.f;
            out[2 * MD + 4 * s + 2] = 0.f;
            out[2 * MD + 4 * s + 3] = 0.f;
            out[6 * MD + s] = -1.0f;
            out[7 * MD + s] = 0.f;
        }
    }
}

extern "C" void kernel_launch(void* const* d_in, const int* in_sizes, int n_in,
                              void* d_out, int out_size, void* d_ws, size_t ws_size,
                              hipStream_t stream) {
    const float* anchors = (const float*)d_in[1];
    const float* reg     = (const float*)d_in[2];
    const float* cls     = (const float*)d_in[3];
    float* out = (float*)d_out;
    char* ws = (char*)d_ws;

    u32* sbits  = (u32*)(ws + 0);
    u32* amax   = (u32*)(ws + 1000000);
    u32* state  = (u32*)(ws + 2000000);
    u32* hist   = (u32*)(ws + 2000064);
    u64* cand   = (u64*)(ws + 2008256);
    u32* canda  = (u32*)(ws + 2041024);
    u32* cands  = (u32*)(ws + 2049216);
    u64* sup    = (u64*)(ws + 2090176);

    hipLaunchKernelGGL(k_score, dim3((NA * 4 + 255) / 256), dim3(256), 0, stream,
                       cls, sbits, amax, state, hist);
    for (int p = 0; p < 3; ++p) {
        hipLaunchKernelGGL(k_hist, dim3((NA + 1023) / 1024), dim3(256), 0, stream,
                           sbits, hist, state, p);
        hipLaunchKernelGGL(k_pick, dim3(1), dim3(64), 0, stream,
                           state, hist, p, (p == 2) ? 1024 : 2048);
    }
    hipLaunchKernelGGL(k_collect, dim3((NA + 255) / 256), dim3(256), 0, stream,
                       sbits, state, cand);
    hipLaunchKernelGGL(k_sort, dim3(1), dim3(1024), 0, stream, state, cand, canda, cands);
    hipLaunchKernelGGL(k_iou, dim3(32, 32), dim3(64), 0, stream, anchors, reg, canda, sup);
    hipLaunchKernelGGL(k_scan, dim3(1), dim3(64), 0, stream,
                       sup, cands, canda, amax, anchors, reg, out);
}

// Round 4
// 132.195 us; speedup vs baseline: 1.9506x; 1.4037x over previous
//
#include <hip/hip_runtime.h>
#include <stdint.h>

typedef unsigned long long u64;
typedef unsigned int u32;

#define NA 250000
#define NC 80
#define KP 2000
#define MD 300
#define CAP 4096
#define SCORE_TH 0.05f

// ---- ws layout (bytes) ----
// sbits  u32[250000]      @ 0
// amax   u32[250000]      @ 1000000
// state  u32[16]          @ 2000000   [0]=prefix [1]=k [2]=pivot [3]=n_cand
// hist   u32[2048]        @ 2000064
// cand   u64[4096]        @ 2008256
// canda  u32[2048]        @ 2041024   (anchor index per sorted candidate)
// cands  u32[2048]        @ 2049216   (score bits per sorted candidate)
// sup    u64[2048*32]     @ 2090176   (suppression bitmask, j>i only)

__device__ __forceinline__ u64 readlane_u64(u64 v, int b) {
    u32 lo = (u32)__builtin_amdgcn_readlane((int)(u32)v, b);
    u32 hi = (u32)__builtin_amdgcn_readlane((int)(u32)(v >> 32), b);
    return ((u64)hi << 32) | lo;
}

__device__ __forceinline__ float4 decode_box(const float* __restrict__ anchors,
                                             const float* __restrict__ reg, u32 a) {
    float4 an = ((const float4*)anchors)[a];
    float4 rg = ((const float4*)reg)[a];
    float w = an.z - an.x, h = an.w - an.y;
    float cx = an.x + 0.5f * w, cy = an.y + 0.5f * h;
    float pcx = cx + (rg.x * 0.1f) * w;
    float pcy = cy + (rg.y * 0.1f) * h;
    float pw = expf(rg.z * 0.2f) * w;
    float ph = expf(rg.w * 0.2f) * h;
    float x1 = fmaxf(pcx - 0.5f * pw, 0.0f);
    float y1 = fmaxf(pcy - 0.5f * ph, 0.0f);
    float x2 = fminf(pcx + 0.5f * pw, 512.0f);
    float y2 = fminf(pcy + 0.5f * ph, 512.0f);
    return make_float4(x1, y1, x2, y2);
}

// scores + argmax (init fused into block 0): 4 lanes per anchor, 5x float4 each
__global__ void k_score(const float* __restrict__ cls, u32* __restrict__ sbits,
                        u32* __restrict__ amax, u32* __restrict__ state,
                        u32* __restrict__ hist) {
    int t = threadIdx.x;
    if (blockIdx.x == 0) {
        if (t < 16) state[t] = (t == 1) ? (u32)KP : 0u;
        for (int i = t; i < 2048; i += 256) hist[i] = 0;
    }
    int tid = blockIdx.x * 256 + t;
    int a = tid >> 2;
    int k = tid & 3;
    if (a >= NA) return;
    const float4* cv = (const float4*)cls;
    int base = a * 20 + k * 5;
    float best = -1e30f; int bi = 0;
#pragma unroll
    for (int j = 0; j < 5; ++j) {
        float4 v = cv[base + j];
        int c0 = k * 20 + j * 4;
        if (v.x > best) { best = v.x; bi = c0; }
        if (v.y > best) { best = v.y; bi = c0 + 1; }
        if (v.z > best) { best = v.z; bi = c0 + 2; }
        if (v.w > best) { best = v.w; bi = c0 + 3; }
    }
#pragma unroll
    for (int m = 1; m <= 2; m <<= 1) {
        float ob = __shfl_xor(best, m);
        int   oi = __shfl_xor(bi, m);
        if (ob > best || (ob == best && oi < bi)) { best = ob; bi = oi; }
    }
    if (k == 0) {
        sbits[a] = (best > SCORE_TH) ? __float_as_uint(best) : 0u;
        amax[a] = (u32)bi;
    }
}

// radix-select histogram pass (p=0: bits>>21 [2048 bins]; p=1: (>>10)&0x7FF; p=2: &0x3FF)
__global__ void k_hist(const u32* __restrict__ sbits, u32* __restrict__ hist,
                       const u32* __restrict__ state, int p) {
    __shared__ u32 lh[2048];
    int t = threadIdx.x;
    for (int i = t; i < 2048; i += 256) lh[i] = 0;
    __syncthreads();
    u32 prefix = state[0];
    int idx = blockIdx.x * 1024 + t;
#pragma unroll
    for (int r = 0; r < 4; ++r) {
        int a = idx + r * 256;
        if (a < NA) {
            u32 b = sbits[a];
            bool ok; u32 d;
            if (p == 0)      { ok = true;                      d = b >> 21; }
            else if (p == 1) { ok = ((b >> 21) == prefix);     d = (b >> 10) & 0x7FFu; }
            else             { ok = ((b >> 10) == prefix);     d = b & 0x3FFu; }
            if (ok) atomicAdd(&lh[d], 1u);
        }
    }
    __syncthreads();
    for (int i = t; i < 2048; i += 256) { u32 h = lh[i]; if (h) atomicAdd(&hist[i], h); }
}

__global__ void k_pick(u32* state, u32* hist, int p, int nbins) {
    int lane = threadIdx.x;                  // 64 threads
    int per = nbins >> 6;
    int hi = nbins - lane * per;
    int lo = hi - per;
    u32 s = 0;
    for (int b = lo; b < hi; ++b) s += hist[b];
    u32 sc = s;
#pragma unroll
    for (int d = 1; d < 64; d <<= 1) {
        u32 tv = __shfl_up(sc, d);
        if (lane >= d) sc += tv;
    }
    u32 pre = sc - s;
    u32 kk = state[1];
    if (pre < kk && kk <= sc) {              // exactly one lane
        u32 c = pre; int B = lo;
        for (int b = hi - 1; b >= lo; --b) {
            u32 h = hist[b];
            if (c + h >= kk) { B = b; state[1] = kk - c; break; }
            c += h;
        }
        u32 prefix = state[0];
        if (p == 0)      state[0] = (u32)B;
        else if (p == 1) state[0] = (prefix << 11) | (u32)B;
        else             state[2] = (prefix << 10) | (u32)B;   // final pivot
    }
    for (int i = lane; i < 2048; i += 64) hist[i] = 0;
}

__global__ void k_collect(const u32* __restrict__ sbits, u32* state, u64* __restrict__ cand) {
    int a = blockIdx.x * 256 + threadIdx.x;
    if (a >= NA) return;
    u32 b = sbits[a];
    u32 pivot = state[2];
    if (b != 0u && b >= pivot) {
        u32 slot = atomicAdd(&state[3], 1u);
        if (slot < CAP) cand[slot] = ((u64)b << 32) | (u32)(~(u32)a); // (score desc, idx asc)
    }
}

// rank-sort: each candidate's final slot = #{keys greater}. 64 blocks x 256 threads;
// wave q of a block counts segment [q*1024,(q+1)*1024) via LDS broadcast reads.
__global__ __launch_bounds__(256) void k_rank(const u32* __restrict__ state,
                                              const u64* __restrict__ cand,
                                              u32* __restrict__ canda, u32* __restrict__ cands) {
    __shared__ u64 tile[CAP];        // 32 KB
    __shared__ u32 pr[4 * 64];
    int tid = threadIdx.x;
    int n = (int)state[3]; if (n > CAP) n = CAP;
    for (int i = tid; i < CAP; i += 256) tile[i] = (i < n) ? cand[i] : 0ull;
    __syncthreads();
    int q = tid >> 6;                // wave id 0..3
    int c = tid & 63;
    int idx = blockIdx.x * 64 + c;   // candidate index
    u64 my = tile[idx];
    int j0 = q * 1024;
    int j1 = j0 + 1024; if (j1 > n) j1 = n;
    u32 rank = 0;
#pragma unroll 4
    for (int j = j0; j < j1; ++j) rank += (tile[j] > my) ? 1u : 0u;
    pr[q * 64 + c] = rank;
    __syncthreads();
    if (q == 0) {
        u32 rk = pr[c] + pr[64 + c] + pr[128 + c] + pr[192 + c];
        if (idx < n) {
            if (rk < 2048u) {
                canda[rk] = ~((u32)my);
                cands[rk] = (u32)(my >> 32);
            }
        } else if (idx < 2048) {
            canda[idx] = 0u;
            cands[idx] = 0u;
        }
    }
}

// IoU suppression bitmask with inline box decode.
__global__ void k_iou(const float* __restrict__ anchors, const float* __restrict__ reg,
                      const u32* __restrict__ canda, u64* __restrict__ sup) {
    int bi = blockIdx.y, bj = blockIdx.x;
    int t = threadIdx.x;
    int i = bi * 64 + t;
    if (bj < bi) { if (i < KP) sup[(size_t)i * 32 + bj] = 0ull; return; }
    __shared__ float4 jb[64];
    int j0 = bj * 64;
    int j = j0 + t;                               // j <= 2047
    int jn = KP - j0; if (jn > 64) jn = 64;
    u32 ja = canda[j]; if (ja >= NA) ja = 0;
    float4 jbox = decode_box(anchors, reg, ja);
    jb[t] = jbox;
    __syncthreads();
    if (i >= KP) return;
    float4 bx;
    if (bi == bj) bx = jbox;
    else { u32 ia = canda[i]; if (ia >= NA) ia = 0; bx = decode_box(anchors, reg, ia); }
    float ai = (bx.z - bx.x) * (bx.w - bx.y);
    u64 word = 0ull;
    for (int jj = 0; jj < jn; ++jj) {
        if (j0 + jj <= i) continue;
        float4 b2 = jb[jj];
        float aj = (b2.z - b2.x) * (b2.w - b2.y);
        float xx1 = fmaxf(bx.x, b2.x), yy1 = fmaxf(bx.y, b2.y);
        float xx2 = fminf(bx.z, b2.z), yy2 = fminf(bx.w, b2.w);
        float iw = xx2 - xx1; if (iw < 0.f) iw = 0.f;
        float ih = yy2 - yy1; if (ih < 0.f) ih = 0.f;
        float inter = iw * ih;
        float iou = inter / (ai + aj - inter + 1e-9f);
        if (iou > 0.1f) word |= (1ull << jj);
    }
    sup[(size_t)i * 32 + bj] = word;
}

// serial greedy NMS + fused output, single wave, fully unrolled 32 chunks.
// Rows live in registers (depth-2 prefetch, static indices). The next chunk's
// suppression word is accumulated in `carry` during the serial loop (readlane of
// word c+1, off the rem-update chain), so the LDS transpose-fold of kept rows is
// delayed one chunk and off the critical path.
__global__ __launch_bounds__(64, 1) void k_scan(const u64* __restrict__ sup,
                                                const u32* __restrict__ cands,
                                                const u32* __restrict__ canda,
                                                const u32* __restrict__ amax,
                                                const float* __restrict__ anchors,
                                                const float* __restrict__ reg,
                                                float* __restrict__ out) {
    __shared__ u64 rows[2][32 * 65];   // [buf][word*65 + row]
    __shared__ int klist[2048];
    int lane = threadIdx.x;

    ulonglong2 bufA[16], bufB[16];
    float cvA, cvB;
    {
        const ulonglong2* s0 = (const ulonglong2*)(sup + (size_t)lane * 32);
#pragma unroll
        for (int q = 0; q < 16; ++q) bufA[q] = s0[q];
        cvA = __uint_as_float(cands[lane]);
        const ulonglong2* s1 = (const ulonglong2*)(sup + (size_t)(64 + lane) * 32);
#pragma unroll
        for (int q = 0; q < 16; ++q) bufB[q] = s1[q];
        cvB = __uint_as_float(cands[64 + lane]);
    }

    u64 removed = 0ull;      // lane w<32 holds word w, folds complete through chunk c-2
    u64 carry = 0ull;        // chunk (c)'s suppression word from chunk c-1's kept
    u64 kmask_prev = 0ull;
    int kc = 0;

#pragma unroll
    for (int c = 0; c < 32; ++c) {
        const int p = c & 1;
        ulonglong2* buf = p ? bufB : bufA;
        float cv = p ? cvB : cvA;

        // publish this chunk's rows to LDS (consumed by the fold during chunk c+1)
#pragma unroll
        for (int q = 0; q < 16; ++q) {
            rows[p][(2 * q) * 65 + lane] = buf[q].x;
            rows[p][(2 * q + 1) * 65 + lane] = buf[q].y;
        }

        u64 curw = carry | readlane_u64(removed, c);
        u64 vm = __ballot(cv > SCORE_TH);
        if (c == 31) vm &= (1ull << (KP - 31 * 64)) - 1ull;

        u64 myw = (c & 1) ? buf[c >> 1].y : buf[c >> 1].x;           // word c of my row
        u64 myw1 = (c < 31) ? ((c & 1) ? buf[(c + 1) >> 1].x : buf[c >> 1].y) : 0ull;

        // serial greedy: rem/curw uniform (SALU); readlane with SGPR index
        u64 rem = vm & ~curw;
        u64 kmask = 0ull, ncarry = 0ull;
        while (rem) {
            int b = (int)__builtin_ctzll(rem);
            kmask |= (1ull << b);
            curw |= readlane_u64(myw, b);
            ncarry |= readlane_u64(myw1, b);
            rem &= ~curw;
            rem &= ~(1ull << b);
        }

        // fold PREVIOUS chunk's kept rows into removed (slack: consumed at c+1)
        if (lane < 32 && kmask_prev) {
            const u64* rb = &rows[p ^ 1][lane * 65];
            u64 t = kmask_prev;
            while (t) {
                int b0 = (int)__builtin_ctzll(t); t &= t - 1;
                int b1 = b0, b2 = b0, b3 = b0, b4 = b0, b5 = b0, b6 = b0, b7 = b0;
                if (t) { b1 = (int)__builtin_ctzll(t); t &= t - 1; }
                if (t) { b2 = (int)__builtin_ctzll(t); t &= t - 1; }
                if (t) { b3 = (int)__builtin_ctzll(t); t &= t - 1; }
                if (t) { b4 = (int)__builtin_ctzll(t); t &= t - 1; }
                if (t) { b5 = (int)__builtin_ctzll(t); t &= t - 1; }
                if (t) { b6 = (int)__builtin_ctzll(t); t &= t - 1; }
                if (t) { b7 = (int)__builtin_ctzll(t); t &= t - 1; }
                removed |= rb[b0] | rb[b1] | rb[b2] | rb[b3] | rb[b4] | rb[b5] | rb[b6] | rb[b7];
            }
        }

        if ((kmask >> lane) & 1ull) {
            int pos = kc + (int)__popcll(kmask & ((1ull << lane) - 1ull));
            klist[pos] = c * 64 + lane;
        }
        kc += (int)__popcll(kmask);
        kmask_prev = kmask;
        carry = ncarry;

        // prefetch chunk c+2 into the buffer just consumed
        if (c < 30) {
            int r = (c + 2) * 64 + lane;
            int rr = (r >= KP) ? 0 : r;
            const ulonglong2* s2 = (const ulonglong2*)(sup + (size_t)rr * 32);
#pragma unroll
            for (int q = 0; q < 16; ++q) buf[q] = s2[q];
            float ncv = __uint_as_float(cands[r]);
            if (p) cvB = ncv; else cvA = ncv;
        }
    }

    // fused output: 300 slots, batched gathers
    int myci[5];
    u32 mya[5];
#pragma unroll
    for (int r = 0; r < 5; ++r) {
        int s = lane + r * 64;
        myci[r] = (s < MD && s < kc) ? klist[s] : -1;
    }
#pragma unroll
    for (int r = 0; r < 5; ++r) mya[r] = (myci[r] >= 0) ? canda[myci[r]] : 0u;
#pragma unroll
    for (int r = 0; r < 5; ++r) {
        int s = lane + r * 64;
        if (s >= MD) continue;
        if (myci[r] >= 0) {
            int ci = myci[r];
            u32 a = mya[r];
            u32 aa = (a >= NA) ? 0u : a;
            float4 bx = decode_box(anchors, reg, aa);
            out[s] = __uint_as_float(cands[ci]);
            out[MD + s] = (float)amax[aa];
            out[2 * MD + 4 * s + 0] = bx.x;
            out[2 * MD + 4 * s + 1] = bx.y;
            out[2 * MD + 4 * s + 2] = bx.z;
            out[2 * MD + 4 * s + 3] = bx.w;
            out[6 * MD + s] = (float)a;
            out[7 * MD + s] = 1.0f;
        } else {
            out[s] = 0.f;
            out[MD + s] = 0.f;
            out[2 * MD + 4 * s + 0] = 0.f;
            out[2 * MD + 4 * s + 1] = 0.f;
            out[2 * MD + 4 * s + 2] = 0.f;
            out[2 * MD + 4 * s + 3] = 0.f;
            out[6 * MD + s] = -1.0f;
            out[7 * MD + s] = 0.f;
        }
    }
}

extern "C" void kernel_launch(void* const* d_in, const int* in_sizes, int n_in,
                              void* d_out, int out_size, void* d_ws, size_t ws_size,
                              hipStream_t stream) {
    const float* anchors = (const float*)d_in[1];
    const float* reg     = (const float*)d_in[2];
    const float* cls     = (const float*)d_in[3];
    float* out = (float*)d_out;
    char* ws = (char*)d_ws;

    u32* sbits  = (u32*)(ws + 0);
    u32* amax   = (u32*)(ws + 1000000);
    u32* state  = (u32*)(ws + 2000000);
    u32* hist   = (u32*)(ws + 2000064);
    u64* cand   = (u64*)(ws + 2008256);
    u32* canda  = (u32*)(ws + 2041024);
    u32* cands  = (u32*)(ws + 2049216);
    u64* sup    = (u64*)(ws + 2090176);

    hipLaunchKernelGGL(k_score, dim3((NA * 4 + 255) / 256), dim3(256), 0, stream,
                       cls, sbits, amax, state, hist);
    for (int p = 0; p < 3; ++p) {
        hipLaunchKernelGGL(k_hist, dim3((NA + 1023) / 1024), dim3(256), 0, stream,
                           sbits, hist, state, p);
        hipLaunchKernelGGL(k_pick, dim3(1), dim3(64), 0, stream,
                           state, hist, p, (p == 2) ? 1024 : 2048);
    }
    hipLaunchKernelGGL(k_collect, dim3((NA + 255) / 256), dim3(256), 0, stream,
                       sbits, state, cand);
    hipLaunchKernelGGL(k_rank, dim3(64), dim3(256), 0, stream, state, cand, canda, cands);
    hipLaunchKernelGGL(k_iou, dim3(32, 32), dim3(64), 0, stream, anchors, reg, canda, sup);
    hipLaunchKernelGGL(k_scan, dim3(1), dim3(64), 0, stream,
                       sup, cands, canda, amax, anchors, reg, out);
}